// Round 6
// baseline (19595.233 us; speedup 1.0000x reference)
//
#include <hip/hip_runtime.h>
#include <math.h>

// CustomGRU B=64,S=512,F=512,H=1024. FP32 I/O, split-bf16 (hi+lo) MFMA compute.
// Round 6: persistent cooperative kernel with L2-CACHED h exchange.
//   - h/out stores: sc0 sc1 write-through to LLC (no dirty L2 anywhere),
//     drained by vmcnt(0) before barrier arrival.
//   - h loads: PLAIN cacheable (XCD L2 serves 32 wgs) -- round 5's sc0 sc1
//     loads forced 64 MB/step across the die fabric (23.5us/step, 4% MFMA).
//   - ONE acquire fence (flash buffer_inv, no wb walk) per step after the
//     barrier makes the L2-cached reads correct.
//   - Barrier: relaxed counter + separate go-flag line (no polled RMW line).
//   - Epilogue: LDS-staged, wave 0 stores coalesced 16B/8B/8B (round 5 wrote
//     scattered 4B/2B -> WRITE_SIZE 9x ideal). hf state lives in LDS.

#define B_   64
#define S_   512
#define F_   512
#define H_   1024
#define KTOT 1536
#define NG   4096
#define NWG  256
#define NTHR 512
#define RS   1544             // padded LDS row stride (shorts)
#define CPS  260              // Cp tile stride (floats): 16-way conflict -> 4-way
// LDS: Bh/Bl 98816 + Cp 33280 + st_out 1024 + st_hi 512 + st_lo 512 + hf 1024
#define SMEM_BYTES 135168

typedef short short8 __attribute__((ext_vector_type(8)));
typedef float floatx4 __attribute__((ext_vector_type(4)));

__device__ __forceinline__ float bf2f(unsigned short u) {
    union { unsigned int i; float f; } v; v.i = ((unsigned int)u) << 16; return v.f;
}
__device__ __forceinline__ unsigned short f2bf(float f) {
    union { float f; unsigned int i; } v; v.f = f;
    unsigned int x = v.i;
    x += 0x7fffu + ((x >> 16) & 1u);
    return (unsigned short)(x >> 16);
}
__device__ __forceinline__ void split2(float v, unsigned short& hi, unsigned short& lo) {
    hi = f2bf(v);
    lo = f2bf(v - bf2f(hi));
}

__global__ void pack_w(const float* __restrict__ Wih,
                       const float* __restrict__ Whh,
                       unsigned short* __restrict__ Whi,
                       unsigned short* __restrict__ Wlo) {
    int idx = blockIdx.x * 256 + threadIdx.x;   // < NG*KTOT
    int p = idx / KTOT;
    int k = idx - p * KTOT;
    int j = p >> 2, g = p & 3;
    float v = 0.f;
    if (g == 0)      v = (k < F_) ? Wih[k * 3072 + j]        : Whh[(k - F_) * 3072 + j];
    else if (g == 1) v = (k < F_) ? Wih[k * 3072 + 1024 + j] : Whh[(k - F_) * 3072 + 1024 + j];
    else if (g == 2) { if (k <  F_) v = Wih[k * 3072 + 2048 + j]; }
    else             { if (k >= F_) v = Whh[(k - F_) * 3072 + 2048 + j]; }
    unsigned short hi, lo; split2(v, hi, lo);
    Whi[idx] = hi; Wlo[idx] = lo;
}

__global__ void pack_x(const float* __restrict__ x,
                       unsigned short* __restrict__ xhi,
                       unsigned short* __restrict__ xlo) {
    int idx = blockIdx.x * 256 + threadIdx.x;   // < B_*S_*F_
    unsigned short hi, lo; split2(x[idx], hi, lo);
    xhi[idx] = hi; xlo[idx] = lo;
}

// x-side K step: plain cacheable loads (x is read-only)
__device__ __forceinline__ void ks_step_x(floatx4* acc,
    const unsigned short* __restrict__ Ahi, const unsigned short* __restrict__ Alo,
    size_t aofs, const unsigned short* Bh_, const unsigned short* Bl_, int bofs)
{
    short8 bh = *(const short8*)&Bh_[bofs];
    short8 bl = *(const short8*)&Bl_[bofs];
    #pragma unroll
    for (int mt = 0; mt < 4; ++mt) {
        size_t o = aofs + (size_t)mt * ((size_t)16 * S_ * F_);
        short8 ah = *(const short8*)&Ahi[o];
        short8 al = *(const short8*)&Alo[o];
        acc[mt] = __builtin_amdgcn_mfma_f32_16x16x32_bf16(ah, bh, acc[mt], 0, 0, 0);
        acc[mt] = __builtin_amdgcn_mfma_f32_16x16x32_bf16(ah, bl, acc[mt], 0, 0, 0);
        acc[mt] = __builtin_amdgcn_mfma_f32_16x16x32_bf16(al, bh, acc[mt], 0, 0, 0);
    }
}

// h-side K step: plain cacheable loads (L2-served; per-step acquire fence
// invalidates stale L1/L2 copies)
__device__ __forceinline__ void ks_step_h(floatx4* acc,
    const unsigned short* Hhi, const unsigned short* Hlo, size_t aofs,
    const unsigned short* Bh_, const unsigned short* Bl_, int bofs)
{
    short8 bh = *(const short8*)&Bh_[bofs];
    short8 bl = *(const short8*)&Bl_[bofs];
    #pragma unroll
    for (int mt = 0; mt < 4; ++mt) {
        size_t o = aofs + (size_t)mt * (size_t)(16 * H_);
        short8 ah = *(const short8*)&Hhi[o];
        short8 al = *(const short8*)&Hlo[o];
        acc[mt] = __builtin_amdgcn_mfma_f32_16x16x32_bf16(ah, bh, acc[mt], 0, 0, 0);
        acc[mt] = __builtin_amdgcn_mfma_f32_16x16x32_bf16(ah, bl, acc[mt], 0, 0, 0);
        acc[mt] = __builtin_amdgcn_mfma_f32_16x16x32_bf16(al, bh, acc[mt], 0, 0, 0);
    }
}

__global__ __launch_bounds__(NTHR) void gru_persist(
    const unsigned short* __restrict__ xhi,
    const unsigned short* __restrict__ xlo,
    const unsigned short* __restrict__ Whi,
    const unsigned short* __restrict__ Wlo,
    const float* __restrict__ bias,
    unsigned short* hhi0, unsigned short* hlo0,
    unsigned short* hhi1, unsigned short* hlo1,
    float* __restrict__ out,
    float* __restrict__ hlast,
    unsigned* bar)
{
    extern __shared__ char smem[];
    unsigned short* Bh = (unsigned short*)smem;                 // 16 x RS shorts
    unsigned short* Bl = Bh + 16 * RS;
    float* Cp = (float*)(smem + 98816);                         // 32 tiles x CPS f32
    float* st_out = (float*)(smem + 98816 + 33280);             // 256 f32
    unsigned short* st_hi = (unsigned short*)(smem + 98816 + 33280 + 1024); // 256
    unsigned short* st_lo = st_hi + 256;                        // 256
    float* sh_hf = (float*)(smem + 98816 + 33280 + 2048);       // 256 f32

    const int tid = threadIdx.x;
    const int wg  = blockIdx.x;

    // ---- stage this wg's weight slice into LDS (once); init hf state ----
    for (int c = tid; c < 16 * 192; c += NTHR) {
        int row = c / 192, c8 = c - row * 192;
        size_t gofs = (size_t)(wg * 16 + row) * KTOT + c8 * 8;
        *(short8*)&Bh[row * RS + c8 * 8] = *(const short8*)&Whi[gofs];
        *(short8*)&Bl[row * RS + c8 * 8] = *(const short8*)&Wlo[gofs];
    }
    if (tid < 256) sh_hf[tid] = 0.f;
    __syncthreads();

    const int lane = tid & 63;
    const int kw   = tid >> 6;                 // wave id 0..7
    const int l15  = lane & 15, quad = lane >> 4;
    // uniform split: wave kw covers x-K [kw*64,+64) and h-K [kw*128,+128)
    const int xk0   = kw * 64;
    const int hk0   = kw * 128;
    const int bofsx = l15 * RS + xk0 + quad * 8;
    const int bofsh = l15 * RS + 512 + hk0 + quad * 8;

    // epilogue constants (threads 0..255: one (batch eb, col ecol) pair each)
    const int eb   = tid & 63;
    const int ejj  = (tid >> 6) & 3;
    const int ecol = wg * 4 + ejj;
    float bZ = 0.f, bR = 0.f, bE = 0.f;
    if (tid < 256) {
        bZ = bias[ecol];
        bR = bias[H_ + ecol];
        bE = bias[2 * H_ + ecol];
    }
    const int emt = eb >> 4, erow = eb & 15;
    const int elb = (erow >> 2) * 16, err = erow & 3;

    const size_t hrow = (size_t)l15 * H_ + quad * 8;

    for (int t = 0; t < S_; ++t) {
        const unsigned short* hih = (t & 1) ? hhi1 : hhi0;
        const unsigned short* hil = (t & 1) ? hlo1 : hlo0;
        unsigned short* hoh = (t & 1) ? hhi0 : hhi1;
        unsigned short* hol = (t & 1) ? hlo0 : hlo1;

        floatx4 z4 = {0.f, 0.f, 0.f, 0.f};
        floatx4 acc[4] = {z4, z4, z4, z4};

        const size_t xrow = ((size_t)l15 * S_ + t) * F_ + quad * 8;

        #pragma unroll
        for (int ks = 0; ks < 2; ++ks)
            ks_step_x(acc, xhi, xlo, xrow + xk0 + ks * 32, Bh, Bl, bofsx + ks * 32);
        #pragma unroll
        for (int ks = 0; ks < 4; ++ks)
            ks_step_h(acc, hih, hil, hrow + hk0 + ks * 32, Bh, Bl, bofsh + ks * 32);

        #pragma unroll
        for (int mt = 0; mt < 4; ++mt)
            *(floatx4*)&Cp[(kw * 4 + mt) * CPS + lane * 4] = acc[mt];
        __syncthreads();

        // ---- epilogue: gates + h update into LDS staging ----
        if (tid < 256) {
            float g[4];
            #pragma unroll
            for (int gi = 0; gi < 4; ++gi) {
                const int c = ejj * 4 + gi;
                const int base = (elb + c) * 4 + err;
                float s = 0.f;
                #pragma unroll
                for (int k2 = 0; k2 < 8; ++k2)
                    s += Cp[(k2 * 4 + emt) * CPS + base];
                g[gi] = s;
            }
            float z   = 1.f / (1.f + __expf(-(g[0] + bZ)));
            float rr  = 1.f / (1.f + __expf(-(g[1] + bR)));
            float eta = tanhf(g[2] + bE + rr * tanhf(g[3]));
            float ho  = sh_hf[tid];
            float hn  = z * ho + (1.f - z) * eta;
            sh_hf[tid] = hn;
            unsigned short hi, lo; split2(hn, hi, lo);
            st_out[eb * 4 + ejj] = hn;
            st_hi[eb * 4 + ejj]  = hi;
            st_lo[eb * 4 + ejj]  = lo;
        }
        __syncthreads();

        // ---- wave 0: coalesced device-scope stores (write-through to LLC) ----
        if (tid < 64) {
            floatx4 o4 = *(const floatx4*)&st_out[tid * 4];
            unsigned long long h8 = *(const unsigned long long*)&st_hi[tid * 4];
            unsigned long long l8 = *(const unsigned long long*)&st_lo[tid * 4];
            float* po = out + ((size_t)tid * S_ + t) * H_ + wg * 4;
            unsigned short* ph = hoh + tid * H_ + wg * 4;
            unsigned short* pl = hol + tid * H_ + wg * 4;
            asm volatile("global_store_dwordx4 %0, %1, off sc0 sc1" :: "v"(po), "v"(o4) : "memory");
            asm volatile("global_store_dwordx2 %0, %1, off sc0 sc1" :: "v"(ph), "v"(h8) : "memory");
            asm volatile("global_store_dwordx2 %0, %1, off sc0 sc1" :: "v"(pl), "v"(l8) : "memory");
            if (t == S_ - 1) {
                float* pL = hlast + (size_t)tid * H_ + wg * 4;
                asm volatile("global_store_dwordx4 %0, %1, off sc0 sc1" :: "v"(pL), "v"(o4) : "memory");
            }
        }

        // ---- barrier: drain stores, count arrivals, go-flag broadcast ----
        asm volatile("s_waitcnt vmcnt(0)" ::: "memory");
        __syncthreads();
        if (tid == 0) {
            __hip_atomic_fetch_add(&bar[0], 1u, __ATOMIC_RELAXED, __HIP_MEMORY_SCOPE_AGENT);
            if (wg == 0) {
                const unsigned target = (unsigned)(t + 1) * NWG;
                while (__hip_atomic_load(&bar[0], __ATOMIC_RELAXED, __HIP_MEMORY_SCOPE_AGENT) < target)
                    __builtin_amdgcn_s_sleep(2);
                __hip_atomic_store(&bar[16], (unsigned)(t + 1), __ATOMIC_RELAXED, __HIP_MEMORY_SCOPE_AGENT);
            } else {
                while (__hip_atomic_load(&bar[16], __ATOMIC_RELAXED, __HIP_MEMORY_SCOPE_AGENT) < (unsigned)(t + 1))
                    __builtin_amdgcn_s_sleep(2);
            }
        }
        __syncthreads();
        // one flash invalidate (L1+L2 clean lines) -> next step's plain h
        // loads refetch fresh data from LLC. NO release/wbl2 walk anywhere.
        __builtin_amdgcn_fence(__ATOMIC_ACQUIRE, "agent");
    }
}

extern "C" void kernel_launch(void* const* d_in, const int* in_sizes, int n_in,
                              void* d_out, int out_size, void* d_ws, size_t ws_size,
                              hipStream_t stream) {
    const float* x    = (const float*)d_in[0];   // [B,S,F]
    const float* Wih  = (const float*)d_in[1];   // [F,3H]
    const float* Whh  = (const float*)d_in[2];   // [H,3H]
    const float* bias = (const float*)d_in[3];   // [3H]
    float* out = (float*)d_out;                  // [B,S,H] ++ [B,H]

    char* ws = (char*)d_ws;
    unsigned short* Whi = (unsigned short*)ws; ws += (size_t)NG * KTOT * 2;
    unsigned short* Wlo = (unsigned short*)ws; ws += (size_t)NG * KTOT * 2;
    unsigned short* xhi = (unsigned short*)ws; ws += (size_t)B_ * S_ * F_ * 2;
    unsigned short* xlo = (unsigned short*)ws; ws += (size_t)B_ * S_ * F_ * 2;
    unsigned short* hhi0 = (unsigned short*)ws; ws += (size_t)B_ * H_ * 2;
    unsigned short* hlo0 = (unsigned short*)ws; ws += (size_t)B_ * H_ * 2;
    unsigned short* hhi1 = (unsigned short*)ws; ws += (size_t)B_ * H_ * 2;
    unsigned short* hlo1 = (unsigned short*)ws; ws += (size_t)B_ * H_ * 2;
    unsigned* bar = (unsigned*)ws;             ws += 128;

    hipMemsetAsync(hhi0, 0, (size_t)B_ * H_ * 2, stream);
    hipMemsetAsync(hlo0, 0, (size_t)B_ * H_ * 2, stream);
    hipMemsetAsync(bar,  0, 128, stream);

    pack_w<<<(NG * KTOT) / 256, 256, 0, stream>>>(Wih, Whh, Whi, Wlo);
    pack_x<<<(B_ * S_ * F_) / 256, 256, 0, stream>>>(x, xhi, xlo);

    float* hlast = out + (size_t)B_ * S_ * H_;
    void* args[] = { &xhi, &xlo, &Whi, &Wlo, &bias,
                     &hhi0, &hlo0, &hhi1, &hlo1, &out, &hlast, &bar };
    hipLaunchCooperativeKernel((void*)gru_persist, dim3(NWG), dim3(NTHR),
                               args, SMEM_BYTES, stream);
}